// Round 1
// baseline (429.251 us; speedup 1.0000x reference)
//
#include <hip/hip_runtime.h>
#include <hip/hip_bf16.h>

#define M_DIM 4096
#define N_DIM 4096
#define K_DIM 4096
#define BM 128
#define BN 128
#define BK 32
#define NWG ((M_DIM / BM) * (N_DIM / BN)) // 1024

typedef __bf16 bf16x8 __attribute__((ext_vector_type(8)));
typedef float f32x4 __attribute__((ext_vector_type(4)));

__device__ __forceinline__ void async_copy16(const void* g, void* lds) {
    __builtin_amdgcn_global_load_lds(
        (const __attribute__((address_space(1))) void*)g,
        (__attribute__((address_space(3))) void*)lds,
        16, 0, 0);
}

__device__ __forceinline__ ushort f2bf(float f) {
    __hip_bfloat16 h = __float2bfloat16(f);
    return *reinterpret_cast<ushort*>(&h);
}
__device__ __forceinline__ float bf2f(ushort u) {
    __hip_bfloat16 h;
    *reinterpret_cast<ushort*>(&h) = u;
    return __bfloat162float(h);
}

// ---------------- preprocessing: x -> (hi, lo) bf16 split ----------------
__global__ void split_hilo(const float* __restrict__ x, ushort* __restrict__ hi,
                           ushort* __restrict__ lo, int n4) {
    int stride = gridDim.x * blockDim.x;
    for (int idx = blockIdx.x * blockDim.x + threadIdx.x; idx < n4; idx += stride) {
        float4 v = reinterpret_cast<const float4*>(x)[idx];
        float f[4] = {v.x, v.y, v.z, v.w};
        ushort hh[4], ll[4];
#pragma unroll
        for (int j = 0; j < 4; ++j) {
            hh[j] = f2bf(f[j]);
            float r = f[j] - bf2f(hh[j]); // exact (Sterbenz)
            ll[j] = f2bf(r);
        }
        reinterpret_cast<ushort4*>(hi)[idx] = make_ushort4(hh[0], hh[1], hh[2], hh[3]);
        reinterpret_cast<ushort4*>(lo)[idx] = make_ushort4(ll[0], ll[1], ll[2], ll[3]);
    }
}

// ---------------- preprocessing: sign (K,N) fp32 -> Bt (N,K) bf16 ----------------
__global__ void transpose_sign(const float* __restrict__ sgn, ushort* __restrict__ bt) {
    __shared__ float t[32][33];
    int nT = blockIdx.x * 32;
    int kT = blockIdx.y * 32;
    int tx = threadIdx.x; // 0..31
    int ty = threadIdx.y; // 0..7
#pragma unroll
    for (int i = 0; i < 4; ++i)
        t[ty + i * 8][tx] = sgn[(size_t)(kT + ty + i * 8) * N_DIM + nT + tx];
    __syncthreads();
#pragma unroll
    for (int i = 0; i < 4; ++i)
        bt[(size_t)(nT + ty + i * 8) * K_DIM + kT + tx] = f2bf(t[tx][ty + i * 8]);
}

// ---------------- main GEMM: out = (Ahi + Alo) @ Bt^T * s ----------------
// m97-style: 128x128 tile, BK=32, 4 waves (2x2), 4x4 16x16x32 frags/wave,
// global_load_lds width 16, single-buffered LDS, XCD-aware block swizzle.
__global__ __launch_bounds__(256, 2) void gemm_hilo(
    const ushort* __restrict__ Ahi, const ushort* __restrict__ Alo,
    const ushort* __restrict__ Bt, const float* __restrict__ scale_p,
    float* __restrict__ out) {
    __shared__ __align__(16) ushort sAhi[BM * BK];
    __shared__ __align__(16) ushort sAlo[BM * BK];
    __shared__ __align__(16) ushort sB[BN * BK];

    // XCD-aware swizzle (1024 % 8 == 0 -> simple form is bijective)
    int orig = blockIdx.x;
    int wgid = (orig & 7) * (NWG / 8) + (orig >> 3);
    const int bn = N_DIM / BN; // 32
    int bx = wgid % bn;
    int by = wgid / bn;
    int rowBase = by * BM;
    int colBase = bx * BN;

    int tid = threadIdx.x;
    int lane = tid & 63;
    int w = tid >> 6;          // wave 0..3
    int wr = (w >> 1) * 64;    // wave row offset in tile
    int wc = (w & 1) * 64;     // wave col offset in tile

    f32x4 acc[4][4];
#pragma unroll
    for (int i = 0; i < 4; ++i)
#pragma unroll
        for (int j = 0; j < 4; ++j)
            acc[i][j] = f32x4{0.f, 0.f, 0.f, 0.f};

    // staging: tile is 128 rows x 32 k (row-major, ld=BK). 8KB per tile.
    // wave w stages LDS bytes [w*2048, w*2048+2048) in 2 calls of 1KB.
    // lane writes 16B at base + lane*16 -> row = w*32 + c*16 + lane/4, k0 = (lane%4)*8
    int srow = w * 32 + (lane >> 2);
    int sk0 = (lane & 3) * 8;
    const ushort* gA0 = Ahi + (size_t)(rowBase + srow) * K_DIM + sk0;
    const ushort* gA1 = Alo + (size_t)(rowBase + srow) * K_DIM + sk0;
    const ushort* gB0 = Bt + (size_t)(colBase + srow) * K_DIM + sk0;
    ushort* lA0 = sAhi + w * 1024; // elements (w*2048 bytes)
    ushort* lA1 = sAlo + w * 1024;
    ushort* lB0 = sB + w * 1024;
    const int ROWSTEP = 16 * K_DIM; // +16 rows for second call

    int fr = lane & 15;
    int fk = (lane >> 4) * 8;

    for (int kt = 0; kt < K_DIM; kt += BK) {
        const ushort* a0 = gA0 + kt;
        const ushort* a1 = gA1 + kt;
        const ushort* b0 = gB0 + kt;
        async_copy16(a0, lA0);
        async_copy16(a0 + ROWSTEP, lA0 + 512);
        async_copy16(a1, lA1);
        async_copy16(a1 + ROWSTEP, lA1 + 512);
        async_copy16(b0, lB0);
        async_copy16(b0 + ROWSTEP, lB0 + 512);
        __syncthreads(); // compiler drains vmcnt before barrier -> LDS ready

        bf16x8 ah[4], al[4], bb[4];
#pragma unroll
        for (int i = 0; i < 4; ++i) {
            ah[i] = *reinterpret_cast<const bf16x8*>(&sAhi[(wr + i * 16 + fr) * BK + fk]);
            al[i] = *reinterpret_cast<const bf16x8*>(&sAlo[(wr + i * 16 + fr) * BK + fk]);
            bb[i] = *reinterpret_cast<const bf16x8*>(&sB[(wc + i * 16 + fr) * BK + fk]);
        }
#pragma unroll
        for (int i = 0; i < 4; ++i)
#pragma unroll
            for (int j = 0; j < 4; ++j) {
                acc[i][j] = __builtin_amdgcn_mfma_f32_16x16x32_bf16(ah[i], bb[j], acc[i][j], 0, 0, 0);
                acc[i][j] = __builtin_amdgcn_mfma_f32_16x16x32_bf16(al[i], bb[j], acc[i][j], 0, 0, 0);
            }
        __syncthreads();
    }

    // epilogue: scale by softplus(scale). C/D layout: col = lane&15, row = (lane>>4)*4 + r
    float sc = *scale_p;
    float s = (sc > 20.f) ? sc : log1pf(expf(sc));
    int rq = (lane >> 4) * 4;
#pragma unroll
    for (int i = 0; i < 4; ++i)
#pragma unroll
        for (int j = 0; j < 4; ++j)
#pragma unroll
            for (int r = 0; r < 4; ++r) {
                int row = rowBase + wr + i * 16 + rq + r;
                int col = colBase + wc + j * 16 + fr;
                out[(size_t)row * N_DIM + col] = acc[i][j][r] * s;
            }
}

// ---------------- fallback (only if ws too small): naive fp32 tiled GEMM ----------------
__global__ void naive_gemm(const float* __restrict__ x, const float* __restrict__ sgn,
                           const float* __restrict__ scale_p, float* __restrict__ out) {
    __shared__ float sx[16][16];
    __shared__ float sw[16][17];
    int tx = threadIdx.x, ty = threadIdx.y;
    int m = blockIdx.y * 16 + ty;
    int n = blockIdx.x * 16 + tx;
    float acc = 0.f;
    for (int k0 = 0; k0 < K_DIM; k0 += 16) {
        sx[ty][tx] = x[(size_t)m * K_DIM + k0 + tx];
        sw[ty][tx] = sgn[(size_t)(k0 + ty) * N_DIM + n];
        __syncthreads();
#pragma unroll
        for (int kk = 0; kk < 16; ++kk) acc += sx[ty][kk] * sw[kk][tx];
        __syncthreads();
    }
    float sc = *scale_p;
    float s = (sc > 20.f) ? sc : log1pf(expf(sc));
    out[(size_t)m * N_DIM + n] = acc * s;
}

extern "C" void kernel_launch(void* const* d_in, const int* in_sizes, int n_in,
                              void* d_out, int out_size, void* d_ws, size_t ws_size,
                              hipStream_t stream) {
    const float* x = (const float*)d_in[0];
    const float* sgn = (const float*)d_in[1];
    const float* scale_p = (const float*)d_in[2];
    float* out = (float*)d_out;

    const size_t elemsA = (size_t)M_DIM * K_DIM;
    const size_t elemsB = (size_t)K_DIM * N_DIM;
    const size_t need = elemsA * 2 * sizeof(ushort) + elemsB * sizeof(ushort); // 96 MB

    if (ws_size < need) {
        dim3 grid(N_DIM / 16, M_DIM / 16), blk(16, 16);
        naive_gemm<<<grid, blk, 0, stream>>>(x, sgn, scale_p, out);
        return;
    }

    ushort* Ahi = (ushort*)d_ws;
    ushort* Alo = Ahi + elemsA;
    ushort* Bt = Alo + elemsA;

    split_hilo<<<2048, 256, 0, stream>>>(x, Ahi, Alo, (int)(elemsA / 4));
    transpose_sign<<<dim3(N_DIM / 32, K_DIM / 32), dim3(32, 8), 0, stream>>>(sgn, Bt);
    gemm_hilo<<<NWG, 256, 0, stream>>>(Ahi, Alo, Bt, scale_p, out);
}

// Round 2
// 404.901 us; speedup vs baseline: 1.0601x; 1.0601x over previous
//
#include <hip/hip_runtime.h>
#include <hip/hip_bf16.h>

#define MD 4096
#define ND 4096
#define KD 4096   // original K
#define KE 8192   // extended K: [hi | lo]
#define BM 256
#define BN 256
#define BK 64

typedef __bf16 bf16x8 __attribute__((ext_vector_type(8)));
typedef float f32x4 __attribute__((ext_vector_type(4)));
typedef unsigned short u16x8 __attribute__((ext_vector_type(8)));

__device__ __forceinline__ void async_copy16(const void* g, void* lds) {
    __builtin_amdgcn_global_load_lds(
        (const __attribute__((address_space(1))) void*)g,
        (__attribute__((address_space(3))) void*)lds, 16, 0, 0);
}
__device__ __forceinline__ ushort f2bf(float f) {
    __hip_bfloat16 h = __float2bfloat16(f);
    return *reinterpret_cast<ushort*>(&h);
}
__device__ __forceinline__ float bf2f(ushort u) {
    __hip_bfloat16 h;
    *reinterpret_cast<ushort*>(&h) = u;
    return __bfloat162float(h);
}

// ---- x (4096x4096 f32) -> Aext (4096x8192 bf16) = [hi | lo] per row ----
__global__ void split_hilo(const float* __restrict__ x, ushort* __restrict__ a) {
    int gid = blockIdx.x * 256 + threadIdx.x; // 0 .. 2M-1
    int m = gid >> 9;
    int k0 = (gid & 511) << 3;
    const float4* p = (const float4*)(x + (size_t)m * KD + k0);
    float4 v0 = p[0], v1 = p[1];
    float f[8] = {v0.x, v0.y, v0.z, v0.w, v1.x, v1.y, v1.z, v1.w};
    u16x8 hi, lo;
#pragma unroll
    for (int j = 0; j < 8; ++j) {
        ushort h = f2bf(f[j]);
        hi[j] = h;
        lo[j] = f2bf(f[j] - bf2f(h)); // x - bf16(x) exact in f32
    }
    *(u16x8*)(a + (size_t)m * KE + k0) = hi;
    *(u16x8*)(a + (size_t)m * KE + KD + k0) = lo;
}

// ---- sign (K,N) f32 -> Bt (N,K) bf16, 64x64 tiles, 16B stores ----
__global__ void transpose_sign(const float* __restrict__ sgn, ushort* __restrict__ bt) {
    __shared__ float t[64][65];
    int nT = blockIdx.x * 64, kT = blockIdx.y * 64;
    int tid = threadIdx.x;
    int rr = tid >> 4;           // 0..15
    int cc = (tid & 15) * 4;     // 0..60
#pragma unroll
    for (int it = 0; it < 4; ++it) {
        int k = rr + it * 16;
        float4 v = *(const float4*)(sgn + (size_t)(kT + k) * ND + nT + cc);
        t[k][cc] = v.x; t[k][cc + 1] = v.y; t[k][cc + 2] = v.z; t[k][cc + 3] = v.w;
    }
    __syncthreads();
    int n0 = tid >> 3;           // 0..31
    int k0 = (tid & 7) * 8;      // 0..56
#pragma unroll
    for (int it = 0; it < 2; ++it) {
        int n = n0 + it * 32;
        u16x8 u;
#pragma unroll
        for (int j = 0; j < 8; ++j) u[j] = f2bf(t[k0 + j][n]);
        *(u16x8*)(bt + (size_t)(nT + n) * KD + kT + k0) = u;
    }
}

// ---- 256x256 8-phase GEMM, K=8192 (hi|lo), B wraps at 4096 ----
#define BAR() asm volatile("s_barrier" ::: "memory")
#define WAITV(n) asm volatile("s_waitcnt vmcnt(" #n ")" ::: "memory")

#define STAGE_A(buf, t) do { int ko = (t) * 64;                                          \
    async_copy16(srcA0 + ko,                    smA + (buf)*32768 + wOff);               \
    async_copy16(srcA1 + ko,                    smA + (buf)*32768 + 8192 + wOff);        \
    async_copy16(srcA0 + 128 * (size_t)KE + ko, smA + (buf)*32768 + 16384 + wOff);       \
    async_copy16(srcA1 + 128 * (size_t)KE + ko, smA + (buf)*32768 + 16384 + 8192 + wOff);\
} while (0)

#define STAGE_B(buf, t) do { int ko = ((t) * 64) & 4095;                                 \
    async_copy16(srcB0 + ko,                    smB + (buf)*32768 + wOff);               \
    async_copy16(srcB1 + ko,                    smB + (buf)*32768 + 8192 + wOff);        \
    async_copy16(srcB0 + 128 * (size_t)KD + ko, smB + (buf)*32768 + 16384 + wOff);       \
    async_copy16(srcB1 + 128 * (size_t)KD + ko, smB + (buf)*32768 + 16384 + 8192 + wOff);\
} while (0)

#define READ_A(buf, ig) do { _Pragma("unroll") for (int ii = 0; ii < 4; ++ii) {          \
    Af[ii][0] = *(const bf16x8*)(smA + (buf)*32768 + rdA + ((ig)*4 + ii) * 2048);        \
    Af[ii][1] = *(const bf16x8*)(smA + (buf)*32768 + rdA + ((ig)*4 + ii) * 2048 + 64); } \
} while (0)

#define READ_B(buf, jg) do { _Pragma("unroll") for (int jj = 0; jj < 2; ++jj) {          \
    Bf[(jg)*2 + jj][0] = *(const bf16x8*)(smB + (buf)*32768 + rdB + ((jg)*2 + jj) * 2048);      \
    Bf[(jg)*2 + jj][1] = *(const bf16x8*)(smB + (buf)*32768 + rdB + ((jg)*2 + jj) * 2048 + 64); } \
} while (0)

#define MFMAQ(ig, jg) do {                                                               \
    _Pragma("unroll") for (int ii = 0; ii < 4; ++ii)                                     \
    _Pragma("unroll") for (int jj = 0; jj < 2; ++jj) {                                   \
        acc[(ig)*4 + ii][(jg)*2 + jj] = __builtin_amdgcn_mfma_f32_16x16x32_bf16(         \
            Af[ii][0], Bf[(jg)*2 + jj][0], acc[(ig)*4 + ii][(jg)*2 + jj], 0, 0, 0);      \
        acc[(ig)*4 + ii][(jg)*2 + jj] = __builtin_amdgcn_mfma_f32_16x16x32_bf16(         \
            Af[ii][1], Bf[(jg)*2 + jj][1], acc[(ig)*4 + ii][(jg)*2 + jj], 0, 0, 0); }    \
} while (0)

#define EXEC_MFMA(ig, jg) do {                                                           \
    BAR();                                                                               \
    asm volatile("s_waitcnt lgkmcnt(0)" ::: "memory");                                   \
    __builtin_amdgcn_sched_barrier(0);                                                   \
    __builtin_amdgcn_s_setprio(1);                                                       \
    MFMAQ(ig, jg);                                                                       \
    __builtin_amdgcn_s_setprio(0);                                                       \
    BAR();                                                                               \
} while (0)

__global__ __launch_bounds__(512, 2) void gemm8(const ushort* __restrict__ A,
                                                const ushort* __restrict__ Bt,
                                                const float* __restrict__ scale_p,
                                                float* __restrict__ out) {
    __shared__ ushort lds[65536]; // 128 KiB: A 64K | B 64K, each 2 bufs x 2 halves x 16KB
    char* smA = (char*)lds;
    char* smB = smA + 65536;

    int orig = blockIdx.x;                    // 256 WGs, 256 % 8 == 0 -> bijective
    int wgid = (orig & 7) * 32 + (orig >> 3); // XCD swizzle
    int rowBase = (wgid >> 4) * BM;
    int colBase = (wgid & 15) * BN;

    int tid = threadIdx.x;
    int lane = tid & 63;
    int w = tid >> 6; // 0..7
    int wm = w >> 2;  // 0..1
    int wn = w & 3;   // 0..3
    int wOff = w * 1024;

    // --- staging source addresses: linear LDS dest d -> logical (row,col) via
    // st_16x32 involution b = d ^ (((d>>9)&1)<<5); global src pre-swizzled ---
    int dA0 = wOff + lane * 16;
    int dA1 = dA0 + 8192;
    int b0 = dA0 ^ (((dA0 >> 9) & 1) << 5);
    int b1 = dA1 ^ (((dA1 >> 9) & 1) << 5);
    int r0 = b0 >> 7, c0 = (b0 & 127) >> 1;
    int r1 = b1 >> 7, c1 = (b1 & 127) >> 1;
    const ushort* srcA0 = A + (size_t)(rowBase + r0) * KE + c0;
    const ushort* srcA1 = A + (size_t)(rowBase + r1) * KE + c1;
    const ushort* srcB0 = Bt + (size_t)(colBase + r0) * KD + c0;
    const ushort* srcB1 = Bt + (size_t)(colBase + r1) * KD + c1;

    // --- ds_read bases (swizzle folded: adds >= bit6 commute with bit-5 XOR) ---
    int xb = (lane & 15) * 128 + (lane >> 4) * 16;
    int swz = ((lane >> 2) & 1) << 5; // row bit2 of (lane&15)
    int rdA = (xb ^ swz) + wm * 16384;
    int rdB = 65536 + (xb ^ swz) + (wn >> 1) * 16384 + (wn & 1) * 8192;

    f32x4 acc[8][4];
#pragma unroll
    for (int i = 0; i < 8; ++i)
#pragma unroll
        for (int j = 0; j < 4; ++j) acc[i][j] = f32x4{0.f, 0.f, 0.f, 0.f};
    bf16x8 Af[4][2], Bf[4][2];

    // rdB region lives in smB; fold base pointer so macros use one array base
    // (rdB already includes +65536 so index off smA)
#undef READ_B
#define READ_B(buf, jg) do { _Pragma("unroll") for (int jj = 0; jj < 2; ++jj) {          \
    Bf[(jg)*2 + jj][0] = *(const bf16x8*)(smA + (buf)*32768 + rdB + ((jg)*2 + jj) * 2048);      \
    Bf[(jg)*2 + jj][1] = *(const bf16x8*)(smA + (buf)*32768 + rdB + ((jg)*2 + jj) * 2048 + 64); } \
} while (0)

    // ---- prologue: stage tiles 0 (buf0) and 1 (buf1); wait tile0 ----
    STAGE_B(0, 0); STAGE_A(0, 0);
    STAGE_B(1, 1); STAGE_A(1, 1);
    WAITV(8);
    BAR();

    // ---- main loop: iter i computes tiles 2i (buf0), 2i+1 (buf1);
    //      stages 2i+2 (buf0), 2i+3 (buf1). vmcnt(8) only at P4/P8. ----
    for (int i = 0; i < 63; ++i) {
        int t2 = 2 * i + 2, t3 = 2 * i + 3;
        // P1
        READ_A(0, 0); READ_B(0, 0);
        EXEC_MFMA(0, 0);
        // P2
        READ_B(0, 1);
        EXEC_MFMA(0, 1);
        // P3 (buf0 B reads all drained by P2 barrier -> safe to restage B)
        READ_A(0, 1); STAGE_B(0, t2);
        EXEC_MFMA(1, 1);
        // P4 (buf0 A reads drained by P3 barrier)
        STAGE_A(0, t2); WAITV(8); // tile 2i+1 fully landed
        EXEC_MFMA(1, 0);
        // P5
        READ_A(1, 0); READ_B(1, 0);
        EXEC_MFMA(0, 0);
        // P6
        READ_B(1, 1);
        EXEC_MFMA(0, 1);
        // P7
        READ_A(1, 1); STAGE_B(1, t3);
        EXEC_MFMA(1, 1);
        // P8
        STAGE_A(1, t3); WAITV(8); // tile 2i+2 fully landed
        EXEC_MFMA(1, 0);
    }
    // ---- epilogue iteration: tiles 126 (buf0), 127 (buf1); no staging ----
    READ_A(0, 0); READ_B(0, 0); EXEC_MFMA(0, 0);
    READ_B(0, 1);               EXEC_MFMA(0, 1);
    READ_A(0, 1);               EXEC_MFMA(1, 1);
    WAITV(0);                   EXEC_MFMA(1, 0); // tile 127 landed
    READ_A(1, 0); READ_B(1, 0); EXEC_MFMA(0, 0);
    READ_B(1, 1);               EXEC_MFMA(0, 1);
    READ_A(1, 1);               EXEC_MFMA(1, 1);
                                EXEC_MFMA(1, 0);

    // ---- C write: col = lane&15, row = (lane>>4)*4 + r ----
    float sc = *scale_p;
    float s = (sc > 20.f) ? sc : log1pf(expf(sc));
    int cq = (lane >> 4) * 4;
    int cr = lane & 15;
#pragma unroll
    for (int i = 0; i < 8; ++i)
#pragma unroll
        for (int j = 0; j < 4; ++j)
#pragma unroll
            for (int r = 0; r < 4; ++r) {
                size_t row = rowBase + wm * 128 + i * 16 + cq + r;
                size_t col = colBase + wn * 64 + j * 16 + cr;
                out[row * ND + col] = acc[i][j][r] * s;
            }
}

// ---- fallback: naive fp32 (only if ws too small) ----
__global__ void naive_gemm(const float* __restrict__ x, const float* __restrict__ sgn,
                           const float* __restrict__ scale_p, float* __restrict__ out) {
    __shared__ float sx[16][16];
    __shared__ float sw[16][17];
    int tx = threadIdx.x, ty = threadIdx.y;
    int m = blockIdx.y * 16 + ty;
    int n = blockIdx.x * 16 + tx;
    float acc = 0.f;
    for (int k0 = 0; k0 < KD; k0 += 16) {
        sx[ty][tx] = x[(size_t)m * KD + k0 + tx];
        sw[ty][tx] = sgn[(size_t)(k0 + ty) * ND + n];
        __syncthreads();
#pragma unroll
        for (int kk = 0; kk < 16; ++kk) acc += sx[ty][kk] * sw[kk][tx];
        __syncthreads();
    }
    float sc = *scale_p;
    float s = (sc > 20.f) ? sc : log1pf(expf(sc));
    out[(size_t)m * ND + n] = acc * s;
}

extern "C" void kernel_launch(void* const* d_in, const int* in_sizes, int n_in,
                              void* d_out, int out_size, void* d_ws, size_t ws_size,
                              hipStream_t stream) {
    const float* x = (const float*)d_in[0];
    const float* sgn = (const float*)d_in[1];
    const float* scale_p = (const float*)d_in[2];
    float* out = (float*)d_out;

    const size_t elemsA = (size_t)MD * KE;      // 64 MB bf16
    const size_t elemsB = (size_t)KD * ND;      // 32 MB bf16
    const size_t need = (elemsA + elemsB) * sizeof(ushort);

    if (ws_size < need) {
        dim3 grid(ND / 16, MD / 16), blk(16, 16);
        naive_gemm<<<grid, blk, 0, stream>>>(x, sgn, scale_p, out);
        return;
    }

    ushort* Aext = (ushort*)d_ws;
    ushort* Bt = Aext + elemsA;

    split_hilo<<<8192, 256, 0, stream>>>(x, Aext);
    transpose_sign<<<dim3(ND / 64, KD / 64), 256, 0, stream>>>(sgn, Bt);
    gemm8<<<256, 512, 0, stream>>>(Aext, Bt, scale_p, out);
}

// Round 6
// 378.138 us; speedup vs baseline: 1.1352x; 1.0708x over previous
//
#include <hip/hip_runtime.h>
#include <hip/hip_bf16.h>

#define MD 4096
#define ND 4096
#define KD 4096   // original K
#define KE 8192   // extended K: [hi | lo]
#define BM 256
#define BN 256
#define BK 64

typedef __bf16 bf16x8 __attribute__((ext_vector_type(8)));
typedef float f32x4 __attribute__((ext_vector_type(4)));
typedef unsigned short u16x8 __attribute__((ext_vector_type(8)));

__device__ __forceinline__ void async_copy16(const void* g, void* lds) {
    __builtin_amdgcn_global_load_lds(
        (const __attribute__((address_space(1))) void*)g,
        (__attribute__((address_space(3))) void*)lds, 16, 0, 0);
}
__device__ __forceinline__ ushort f2bf(float f) {
    __hip_bfloat16 h = __float2bfloat16(f);
    return *reinterpret_cast<ushort*>(&h);
}
__device__ __forceinline__ float bf2f(ushort u) {
    __hip_bfloat16 h;
    *reinterpret_cast<ushort*>(&h) = u;
    return __bfloat162float(h);
}

// ---- fused prep: blocks [0,8192) split x -> [hi|lo]; [8192,12288) transpose sign ----
__global__ void prep(const float* __restrict__ x, const float* __restrict__ sgn,
                     ushort* __restrict__ a, ushort* __restrict__ bt) {
    __shared__ ushort t[64][65];
    int blk = blockIdx.x;
    if (blk < 8192) {
        int gid = blk * 256 + threadIdx.x; // 0 .. 2M-1
        int m = gid >> 9;
        int k0 = (gid & 511) << 3;
        const float4* p = (const float4*)(x + (size_t)m * KD + k0);
        float4 v0 = p[0], v1 = p[1];
        float f[8] = {v0.x, v0.y, v0.z, v0.w, v1.x, v1.y, v1.z, v1.w};
        u16x8 hi, lo;
#pragma unroll
        for (int j = 0; j < 8; ++j) {
            ushort h = f2bf(f[j]);
            hi[j] = h;
            lo[j] = f2bf(f[j] - bf2f(h)); // x - bf16(x) exact in f32
        }
        *(u16x8*)(a + (size_t)m * KE + k0) = hi;
        *(u16x8*)(a + (size_t)m * KE + KD + k0) = lo;
    } else {
        int b = blk - 8192;
        int nT = (b & 63) * 64, kT = (b >> 6) * 64;
        int tid = threadIdx.x;
        int rr = tid >> 4;        // 0..15
        int cc = (tid & 15) * 4;  // 0..60
#pragma unroll
        for (int it = 0; it < 4; ++it) {
            int k = rr + it * 16;
            float4 v = *(const float4*)(sgn + (size_t)(kT + k) * ND + nT + cc);
            const float ff[4] = {v.x, v.y, v.z, v.w};
#pragma unroll
            for (int j = 0; j < 4; ++j) {
                unsigned bits = __float_as_uint(ff[j]);
                t[k][cc + j] = (ushort)(0x3F80u | ((bits >> 16) & 0x8000u));
            }
        }
        __syncthreads();
        int n0 = tid >> 3;        // 0..31
        int k0 = (tid & 7) * 8;   // 0..56
#pragma unroll
        for (int it = 0; it < 2; ++it) {
            int n = n0 + it * 32;
            u16x8 u;
#pragma unroll
            for (int j = 0; j < 8; ++j) u[j] = t[k0 + j][n];
            *(u16x8*)(bt + (size_t)(nT + n) * KD + kT + k0) = u;
        }
    }
}

// ---- 256x256 8-phase GEMM, K=8192 (hi|lo), B wraps at 4096 ----
#define BAR() asm volatile("s_barrier" ::: "memory")
#define WAITV(n) asm volatile("s_waitcnt vmcnt(" #n ")" ::: "memory")

#define STAGE_A(buf, t) do { int ko = (t) * 64;                                           \
    async_copy16(srcA + ko,                          smA + (buf)*32768 + wOff);           \
    async_copy16(srcA + 64 * (size_t)KE + ko,        smA + (buf)*32768 + 8192 + wOff);    \
    async_copy16(srcA + 128 * (size_t)KE + ko,       smA + (buf)*32768 + 16384 + wOff);   \
    async_copy16(srcA + 192 * (size_t)KE + ko,       smA + (buf)*32768 + 24576 + wOff);   \
} while (0)

#define STAGE_B(buf, t) do { int ko = ((t) * 64) & 4095;                                  \
    async_copy16(srcB + ko,                          smB + (buf)*32768 + wOff);           \
    async_copy16(srcB + 64 * (size_t)KD + ko,        smB + (buf)*32768 + 8192 + wOff);    \
    async_copy16(srcB + 128 * (size_t)KD + ko,       smB + (buf)*32768 + 16384 + wOff);   \
    async_copy16(srcB + 192 * (size_t)KD + ko,       smB + (buf)*32768 + 24576 + wOff);   \
} while (0)

#define READ_A(buf, ig) do { _Pragma("unroll") for (int ii = 0; ii < 4; ++ii) {           \
    Af[ii][0] = *(const bf16x8*)(smA + (buf)*32768 + rdA  + ((ig)*4 + ii) * 2048);        \
    Af[ii][1] = *(const bf16x8*)(smA + (buf)*32768 + rdA2 + ((ig)*4 + ii) * 2048); }      \
} while (0)

#define READ_B(buf, jg) do { _Pragma("unroll") for (int jj = 0; jj < 2; ++jj) {           \
    Bf[(jg)*2 + jj][0] = *(const bf16x8*)(smA + (buf)*32768 + rdB  + ((jg)*2 + jj) * 2048); \
    Bf[(jg)*2 + jj][1] = *(const bf16x8*)(smA + (buf)*32768 + rdB2 + ((jg)*2 + jj) * 2048); } \
} while (0)

#define MFMAQ(ig, jg) do {                                                                \
    _Pragma("unroll") for (int ii = 0; ii < 4; ++ii)                                      \
    _Pragma("unroll") for (int jj = 0; jj < 2; ++jj) {                                    \
        acc[(ig)*4 + ii][(jg)*2 + jj] = __builtin_amdgcn_mfma_f32_16x16x32_bf16(          \
            Af[ii][0], Bf[(jg)*2 + jj][0], acc[(ig)*4 + ii][(jg)*2 + jj], 0, 0, 0);       \
        acc[(ig)*4 + ii][(jg)*2 + jj] = __builtin_amdgcn_mfma_f32_16x16x32_bf16(          \
            Af[ii][1], Bf[(jg)*2 + jj][1], acc[(ig)*4 + ii][(jg)*2 + jj], 0, 0, 0); }     \
} while (0)

#define EXEC_MFMA(ig, jg) do {                                                            \
    BAR();                                                                                \
    asm volatile("s_waitcnt lgkmcnt(0)" ::: "memory");                                    \
    __builtin_amdgcn_sched_barrier(0);                                                    \
    __builtin_amdgcn_s_setprio(1);                                                        \
    MFMAQ(ig, jg);                                                                        \
    __builtin_amdgcn_s_setprio(0);                                                        \
    BAR();                                                                                \
} while (0)

__global__ __launch_bounds__(512, 2) void gemm8(const ushort* __restrict__ A,
                                                const ushort* __restrict__ Bt,
                                                const float* __restrict__ scale_p,
                                                float* __restrict__ out) {
    __shared__ ushort lds[65536]; // 128 KiB
    char* smA = (char*)lds;
    char* smB = smA + 65536;

    int orig = blockIdx.x;                    // 256 WGs, 256 % 8 == 0 -> bijective
    int wgid = (orig & 7) * 32 + (orig >> 3); // XCD swizzle
    int rowBase = (wgid >> 4) * BM;
    int colBase = (wgid & 15) * BN;

    int tid = threadIdx.x;
    int lane = tid & 63;
    int w = tid >> 6; // 0..7
    int wm = w >> 2;  // 0..1
    int wn = w & 3;   // 0..3
    int wOff = w * 1024;

    // --- staging: linear LDS dest d holds logical S(d); S(d) = d ^ (((d>>7)&7)<<4).
    // Regions at +8192/+16384/+24576 share the key (64 rows == 0 mod 8) -> same c0.
    int d0 = wOff + lane * 16;                 // [0, 8192)
    int b0 = d0 ^ (((d0 >> 7) & 7) << 4);
    int r0 = b0 >> 7;                          // 0..63 (bits >=7 unchanged)
    int c0 = (b0 & 127) >> 1;                  // col element 0..63
    const ushort* srcA = A + (size_t)(rowBase + r0) * KE + c0;
    const ushort* srcB = Bt + (size_t)(colBase + r0) * KD + c0;

    // --- ds_read: to read logical L, access S(L). key = (row&7)<<4, row = lane&15.
    // Second K=32 half is ^64 (key occupies bit 6; logical +64 has no carry).
    int row = lane & 15;
    int g = lane >> 4;
    int key = (row & 7) << 4;
    int xb = (row * 128 + g * 16) ^ key;
    int rdA = xb + wm * 16384;
    int rdA2 = (xb ^ 64) + wm * 16384;
    int rdB = 65536 + xb + wn * 8192;
    int rdB2 = 65536 + (xb ^ 64) + wn * 8192;

    f32x4 acc[8][4];
#pragma unroll
    for (int i = 0; i < 8; ++i)
#pragma unroll
        for (int j = 0; j < 4; ++j) acc[i][j] = f32x4{0.f, 0.f, 0.f, 0.f};
    bf16x8 Af[4][2], Bf[4][2];

    // ---- prologue: stage tiles 0 (buf0) and 1 (buf1); wait tile0 ----
    STAGE_B(0, 0); STAGE_A(0, 0);
    STAGE_B(1, 1); STAGE_A(1, 1);
    WAITV(8);
    BAR();

    // ---- main loop: iter i computes tiles 2i (buf0), 2i+1 (buf1);
    //      stages 2i+2 (buf0), 2i+3 (buf1). vmcnt(8) only at P4/P8. ----
    for (int i = 0; i < 63; ++i) {
        int t2 = 2 * i + 2, t3 = 2 * i + 3;
        // P1
        READ_A(0, 0); READ_B(0, 0);
        EXEC_MFMA(0, 0);
        // P2
        READ_B(0, 1);
        EXEC_MFMA(0, 1);
        // P3 (buf0 B reads drained by P2 barrier pair)
        READ_A(0, 1); STAGE_B(0, t2);
        EXEC_MFMA(1, 1);
        // P4 (buf0 A reads drained by P3 barrier pair)
        STAGE_A(0, t2); WAITV(8); // tile 2i+1 fully landed
        EXEC_MFMA(1, 0);
        // P5
        READ_A(1, 0); READ_B(1, 0);
        EXEC_MFMA(0, 0);
        // P6
        READ_B(1, 1);
        EXEC_MFMA(0, 1);
        // P7
        READ_A(1, 1); STAGE_B(1, t3);
        EXEC_MFMA(1, 1);
        // P8
        STAGE_A(1, t3); WAITV(8); // tile 2i+2 fully landed
        EXEC_MFMA(1, 0);
    }
    // ---- epilogue iteration: tiles 126 (buf0), 127 (buf1); no staging ----
    READ_A(0, 0); READ_B(0, 0); EXEC_MFMA(0, 0);
    READ_B(0, 1);               EXEC_MFMA(0, 1);
    READ_A(0, 1);               EXEC_MFMA(1, 1);
    WAITV(0);                   EXEC_MFMA(1, 0); // tile 127 landed
    READ_A(1, 0); READ_B(1, 0); EXEC_MFMA(0, 0);
    READ_B(1, 1);               EXEC_MFMA(0, 1);
    READ_A(1, 1);               EXEC_MFMA(1, 1);
                                EXEC_MFMA(1, 0);

    // ---- C write: col = lane&15, row = (lane>>4)*4 + r ----
    float sc = *scale_p;
    float s = (sc > 20.f) ? sc : log1pf(expf(sc));
    int cq = (lane >> 4) * 4;
    int cr = lane & 15;
#pragma unroll
    for (int i = 0; i < 8; ++i)
#pragma unroll
        for (int j = 0; j < 4; ++j)
#pragma unroll
            for (int r = 0; r < 4; ++r) {
                size_t rr_ = rowBase + wm * 128 + i * 16 + cq + r;
                size_t cc_ = colBase + wn * 64 + j * 16 + cr;
                out[rr_ * ND + cc_] = acc[i][j][r] * s;
            }
}

// ---- fallback: naive fp32 (only if ws too small) ----
__global__ void naive_gemm(const float* __restrict__ x, const float* __restrict__ sgn,
                           const float* __restrict__ scale_p, float* __restrict__ out) {
    __shared__ float sx[16][16];
    __shared__ float sw[16][17];
    int tx = threadIdx.x, ty = threadIdx.y;
    int m = blockIdx.y * 16 + ty;
    int n = blockIdx.x * 16 + tx;
    float acc = 0.f;
    for (int k0 = 0; k0 < KD; k0 += 16) {
        sx[ty][tx] = x[(size_t)m * KD + k0 + tx];
        sw[ty][tx] = sgn[(size_t)(k0 + ty) * ND + n];
        __syncthreads();
#pragma unroll
        for (int kk = 0; kk < 16; ++kk) acc += sx[ty][kk] * sw[kk][tx];
        __syncthreads();
    }
    float sc = *scale_p;
    float s = (sc > 20.f) ? sc : log1pf(expf(sc));
    out[(size_t)m * ND + n] = acc * s;
}

extern "C" void kernel_launch(void* const* d_in, const int* in_sizes, int n_in,
                              void* d_out, int out_size, void* d_ws, size_t ws_size,
                              hipStream_t stream) {
    const float* x = (const float*)d_in[0];
    const float* sgn = (const float*)d_in[1];
    const float* scale_p = (const float*)d_in[2];
    float* out = (float*)d_out;

    const size_t elemsA = (size_t)MD * KE;
    const size_t elemsB = (size_t)KD * ND;
    const size_t need = (elemsA + elemsB) * sizeof(ushort);

    if (ws_size < need) {
        dim3 grid(ND / 16, MD / 16), blk(16, 16);
        naive_gemm<<<grid, blk, 0, stream>>>(x, sgn, scale_p, out);
        return;
    }

    ushort* Aext = (ushort*)d_ws;
    ushort* Bt = Aext + elemsA;

    prep<<<12288, 256, 0, stream>>>(x, sgn, Aext, Bt);
    gemm8<<<256, 512, 0, stream>>>(Aext, Bt, scale_p, out);
}

// Round 7
// 277.584 us; speedup vs baseline: 1.5464x; 1.3622x over previous
//
#include <hip/hip_runtime.h>
#include <hip/hip_bf16.h>

#define MD 4096
#define ND 4096
#define KD 4096
#define BM 256
#define BN 256
#define BK 64

typedef __bf16 bf16x8 __attribute__((ext_vector_type(8)));
typedef float f32x4 __attribute__((ext_vector_type(4)));
typedef unsigned short u16x8 __attribute__((ext_vector_type(8)));

__device__ __forceinline__ void async_copy16(const void* g, void* lds) {
    __builtin_amdgcn_global_load_lds(
        (const __attribute__((address_space(1))) void*)g,
        (__attribute__((address_space(3))) void*)lds, 16, 0, 0);
}
__device__ __forceinline__ ushort f2bf(float f) {
    __hip_bfloat16 h = __float2bfloat16(f);
    return *reinterpret_cast<ushort*>(&h);
}

// ---- fused prep: blocks [0,8192) convert x -> bf16; [8192,12288) transpose sign ----
__global__ void prep(const float* __restrict__ x, const float* __restrict__ sgn,
                     ushort* __restrict__ a, ushort* __restrict__ bt) {
    __shared__ ushort t[64][65];
    int blk = blockIdx.x;
    if (blk < 8192) {
        int gid = blk * 256 + threadIdx.x; // 0 .. 2M-1
        int m = gid >> 9;
        int k0 = (gid & 511) << 3;
        const float4* p = (const float4*)(x + (size_t)m * KD + k0);
        float4 v0 = p[0], v1 = p[1];
        float f[8] = {v0.x, v0.y, v0.z, v0.w, v1.x, v1.y, v1.z, v1.w};
        u16x8 hi;
#pragma unroll
        for (int j = 0; j < 8; ++j) hi[j] = f2bf(f[j]); // RNE
        *(u16x8*)(a + (size_t)m * KD + k0) = hi;
    } else {
        int b = blk - 8192;
        int nT = (b & 63) * 64, kT = (b >> 6) * 64;
        int tid = threadIdx.x;
        int rr = tid >> 4;        // 0..15
        int cc = (tid & 15) * 4;  // 0..60
#pragma unroll
        for (int it = 0; it < 4; ++it) {
            int k = rr + it * 16;
            float4 v = *(const float4*)(sgn + (size_t)(kT + k) * ND + nT + cc);
            const float ff[4] = {v.x, v.y, v.z, v.w};
#pragma unroll
            for (int j = 0; j < 4; ++j) {
                unsigned bits = __float_as_uint(ff[j]);
                t[k][cc + j] = (ushort)(0x3F80u | ((bits >> 16) & 0x8000u)); // +-1 bf16
            }
        }
        __syncthreads();
        int n0 = tid >> 3;        // 0..31
        int k0 = (tid & 7) * 8;   // 0..56
#pragma unroll
        for (int it = 0; it < 2; ++it) {
            int n = n0 + it * 32;
            u16x8 u;
#pragma unroll
            for (int j = 0; j < 8; ++j) u[j] = t[k0 + j][n];
            *(u16x8*)(bt + (size_t)(nT + n) * KD + kT + k0) = u;
        }
    }
}

// ---- 256x256 8-phase GEMM, K=4096 bf16 ----
#define BAR() asm volatile("s_barrier" ::: "memory")
#define WAITV(n) asm volatile("s_waitcnt vmcnt(" #n ")" ::: "memory")

#define STAGE_A(buf, t) do { int ko = (t) * 64;                                           \
    async_copy16(srcA + ko,                          smA + (buf)*32768 + wOff);           \
    async_copy16(srcA + 64 * (size_t)KD + ko,        smA + (buf)*32768 + 8192 + wOff);    \
    async_copy16(srcA + 128 * (size_t)KD + ko,       smA + (buf)*32768 + 16384 + wOff);   \
    async_copy16(srcA + 192 * (size_t)KD + ko,       smA + (buf)*32768 + 24576 + wOff);   \
} while (0)

#define STAGE_B(buf, t) do { int ko = (t) * 64;                                           \
    async_copy16(srcB + ko,                          smB + (buf)*32768 + wOff);           \
    async_copy16(srcB + 64 * (size_t)KD + ko,        smB + (buf)*32768 + 8192 + wOff);    \
    async_copy16(srcB + 128 * (size_t)KD + ko,       smB + (buf)*32768 + 16384 + wOff);   \
    async_copy16(srcB + 192 * (size_t)KD + ko,       smB + (buf)*32768 + 24576 + wOff);   \
} while (0)

#define READ_A(buf, ig) do { _Pragma("unroll") for (int ii = 0; ii < 4; ++ii) {           \
    Af[ii][0] = *(const bf16x8*)(smA + (buf)*32768 + rdA  + ((ig)*4 + ii) * 2048);        \
    Af[ii][1] = *(const bf16x8*)(smA + (buf)*32768 + rdA2 + ((ig)*4 + ii) * 2048); }      \
} while (0)

#define READ_B(buf, jg) do { _Pragma("unroll") for (int jj = 0; jj < 2; ++jj) {           \
    Bf[(jg)*2 + jj][0] = *(const bf16x8*)(smA + (buf)*32768 + rdB  + ((jg)*2 + jj) * 2048); \
    Bf[(jg)*2 + jj][1] = *(const bf16x8*)(smA + (buf)*32768 + rdB2 + ((jg)*2 + jj) * 2048); } \
} while (0)

#define MFMAQ(ig, jg) do {                                                                \
    _Pragma("unroll") for (int ii = 0; ii < 4; ++ii)                                      \
    _Pragma("unroll") for (int jj = 0; jj < 2; ++jj) {                                    \
        acc[(ig)*4 + ii][(jg)*2 + jj] = __builtin_amdgcn_mfma_f32_16x16x32_bf16(          \
            Af[ii][0], Bf[(jg)*2 + jj][0], acc[(ig)*4 + ii][(jg)*2 + jj], 0, 0, 0);       \
        acc[(ig)*4 + ii][(jg)*2 + jj] = __builtin_amdgcn_mfma_f32_16x16x32_bf16(          \
            Af[ii][1], Bf[(jg)*2 + jj][1], acc[(ig)*4 + ii][(jg)*2 + jj], 0, 0, 0); }     \
} while (0)

#define EXEC_MFMA(ig, jg) do {                                                            \
    BAR();                                                                                \
    asm volatile("s_waitcnt lgkmcnt(0)" ::: "memory");                                    \
    __builtin_amdgcn_sched_barrier(0);                                                    \
    __builtin_amdgcn_s_setprio(1);                                                        \
    MFMAQ(ig, jg);                                                                        \
    __builtin_amdgcn_s_setprio(0);                                                        \
    BAR();                                                                                \
} while (0)

__global__ __launch_bounds__(512, 2) void gemm8(const ushort* __restrict__ A,
                                                const ushort* __restrict__ Bt,
                                                const float* __restrict__ scale_p,
                                                float* __restrict__ out) {
    __shared__ ushort lds[65536]; // 128 KiB
    char* smA = (char*)lds;
    char* smB = smA + 65536;

    int orig = blockIdx.x;                    // 256 WGs, 256 % 8 == 0 -> bijective
    int wgid = (orig & 7) * 32 + (orig >> 3); // XCD swizzle
    int rowBase = (wgid >> 4) * BM;
    int colBase = (wgid & 15) * BN;

    int tid = threadIdx.x;
    int lane = tid & 63;
    int w = tid >> 6; // 0..7
    int wm = w >> 2;  // 0..1
    int wn = w & 3;   // 0..3
    int wOff = w * 1024;

    // --- staging: linear LDS dest d holds logical S(d); S(d) = d ^ (((d>>7)&7)<<4).
    int d0 = wOff + lane * 16;
    int b0 = d0 ^ (((d0 >> 7) & 7) << 4);
    int r0 = b0 >> 7;
    int c0 = (b0 & 127) >> 1;
    const ushort* srcA = A + (size_t)(rowBase + r0) * KD + c0;
    const ushort* srcB = Bt + (size_t)(colBase + r0) * KD + c0;

    // --- ds_read: to read logical L, access S(L). key = (row&7)<<4, row = lane&15.
    int row = lane & 15;
    int g = lane >> 4;
    int key = (row & 7) << 4;
    int xb = (row * 128 + g * 16) ^ key;
    int rdA = xb + wm * 16384;
    int rdA2 = (xb ^ 64) + wm * 16384;
    int rdB = 65536 + xb + wn * 8192;
    int rdB2 = 65536 + (xb ^ 64) + wn * 8192;

    f32x4 acc[8][4];
#pragma unroll
    for (int i = 0; i < 8; ++i)
#pragma unroll
        for (int j = 0; j < 4; ++j) acc[i][j] = f32x4{0.f, 0.f, 0.f, 0.f};
    bf16x8 Af[4][2], Bf[4][2];

    // ---- prologue: stage tiles 0 (buf0) and 1 (buf1); wait tile0 ----
    STAGE_B(0, 0); STAGE_A(0, 0);
    STAGE_B(1, 1); STAGE_A(1, 1);
    WAITV(8);
    BAR();

    // ---- main loop: iter i computes tiles 2i (buf0), 2i+1 (buf1);
    //      stages 2i+2 (buf0), 2i+3 (buf1). K=4096 -> 64 tiles -> 31 iters. ----
    for (int i = 0; i < 31; ++i) {
        int t2 = 2 * i + 2, t3 = 2 * i + 3;
        // P1
        READ_A(0, 0); READ_B(0, 0);
        EXEC_MFMA(0, 0);
        // P2
        READ_B(0, 1);
        EXEC_MFMA(0, 1);
        // P3
        READ_A(0, 1); STAGE_B(0, t2);
        EXEC_MFMA(1, 1);
        // P4
        STAGE_A(0, t2); WAITV(8); // tile 2i+1 fully landed
        EXEC_MFMA(1, 0);
        // P5
        READ_A(1, 0); READ_B(1, 0);
        EXEC_MFMA(0, 0);
        // P6
        READ_B(1, 1);
        EXEC_MFMA(0, 1);
        // P7
        READ_A(1, 1); STAGE_B(1, t3);
        EXEC_MFMA(1, 1);
        // P8
        STAGE_A(1, t3); WAITV(8); // tile 2i+2 fully landed
        EXEC_MFMA(1, 0);
    }
    // ---- epilogue iteration: tiles 62 (buf0), 63 (buf1); no staging ----
    READ_A(0, 0); READ_B(0, 0); EXEC_MFMA(0, 0);
    READ_B(0, 1);               EXEC_MFMA(0, 1);
    READ_A(0, 1);               EXEC_MFMA(1, 1);
    WAITV(0);                   EXEC_MFMA(1, 0); // tile 63 landed
    READ_A(1, 0); READ_B(1, 0); EXEC_MFMA(0, 0);
    READ_B(1, 1);               EXEC_MFMA(0, 1);
    READ_A(1, 1);               EXEC_MFMA(1, 1);
                                EXEC_MFMA(1, 0);

    // ---- C write: col = lane&15, row = (lane>>4)*4 + r ----
    float sc = *scale_p;
    float s = (sc > 20.f) ? sc : log1pf(expf(sc));
    int cq = (lane >> 4) * 4;
    int cr = lane & 15;
#pragma unroll
    for (int i = 0; i < 8; ++i)
#pragma unroll
        for (int j = 0; j < 4; ++j)
#pragma unroll
            for (int r = 0; r < 4; ++r) {
                size_t rr_ = rowBase + wm * 128 + i * 16 + cq + r;
                size_t cc_ = colBase + wn * 64 + j * 16 + cr;
                out[rr_ * ND + cc_] = acc[i][j][r] * s;
            }
}

// ---- fallback: naive fp32 (only if ws too small) ----
__global__ void naive_gemm(const float* __restrict__ x, const float* __restrict__ sgn,
                           const float* __restrict__ scale_p, float* __restrict__ out) {
    __shared__ float sx[16][16];
    __shared__ float sw[16][17];
    int tx = threadIdx.x, ty = threadIdx.y;
    int m = blockIdx.y * 16 + ty;
    int n = blockIdx.x * 16 + tx;
    float acc = 0.f;
    for (int k0 = 0; k0 < KD; k0 += 16) {
        sx[ty][tx] = x[(size_t)m * KD + k0 + tx];
        sw[ty][tx] = sgn[(size_t)(k0 + ty) * ND + n];
        __syncthreads();
#pragma unroll
        for (int kk = 0; kk < 16; ++kk) acc += sx[ty][kk] * sw[kk][tx];
        __syncthreads();
    }
    float sc = *scale_p;
    float s = (sc > 20.f) ? sc : log1pf(expf(sc));
    out[(size_t)m * ND + n] = acc * s;
}

extern "C" void kernel_launch(void* const* d_in, const int* in_sizes, int n_in,
                              void* d_out, int out_size, void* d_ws, size_t ws_size,
                              hipStream_t stream) {
    const float* x = (const float*)d_in[0];
    const float* sgn = (const float*)d_in[1];
    const float* scale_p = (const float*)d_in[2];
    float* out = (float*)d_out;

    const size_t elemsA = (size_t)MD * KD;
    const size_t elemsB = (size_t)KD * ND;
    const size_t need = (elemsA + elemsB) * sizeof(ushort); // 64 MB

    if (ws_size < need) {
        dim3 grid(ND / 16, MD / 16), blk(16, 16);
        naive_gemm<<<grid, blk, 0, stream>>>(x, sgn, scale_p, out);
        return;
    }

    ushort* Abf = (ushort*)d_ws;
    ushort* Bt = Abf + elemsA;

    prep<<<12288, 256, 0, stream>>>(x, sgn, Abf, Bt);
    gemm8<<<256, 512, 0, stream>>>(Abf, Bt, scale_p, out);
}